// Round 3
// baseline (214.579 us; speedup 1.0000x reference)
//
#include <hip/hip_runtime.h>
#include <hip/hip_bf16.h>

typedef __attribute__((ext_vector_type(8))) short bf16x8;
typedef __attribute__((ext_vector_type(4))) float f32x4;

#define LRELU_ALPHA 0.2f

__device__ __forceinline__ unsigned short f2bf(float x) {
    unsigned u = __float_as_uint(x);
    u += 0x7fffu + ((u >> 16) & 1u);   // RNE; inputs finite
    return (unsigned short)(u >> 16);
}

// ---------------- Stage 1: fused GEMM + row dots + transposed bf16 store ----
// Wh = x @ W^T + bW computed in bf16 MFMA (fp32 accum).
// Writes: WhT[b][f][n] bf16, Wh1[R], Wh2[R] fp32 (dots taken from fp32 acc).
// BM=32 rows, BN=256 (full F), K=256 in 8 steps. 256 thr = 4 waves.
// wave w: wr=w>>1 (16-row half), wc=w&1 (128-f half).
__global__ __launch_bounds__(256) void k_gemm_fused(
    const float* __restrict__ x, const float* __restrict__ W,
    const float* __restrict__ bW, const float* __restrict__ ai,
    const float* __restrict__ bi, const float* __restrict__ aj,
    const float* __restrict__ bj,
    unsigned short* __restrict__ WhT, float* __restrict__ Wh1,
    float* __restrict__ Wh2)
{
    __shared__ alignas(16) unsigned short As[32*40];   // stride 40 elems (80B): conflict-free b128 reads
    __shared__ alignas(16) unsigned short Bs[256*40];
    __shared__ float part1[2][32], part2[2][32];

    const int t = threadIdx.x;
    const int w = t >> 6, l = t & 63;
    const int wr = w >> 1, wc = w & 1;
    const int R0 = blockIdx.x * 32;

    const int srow = t >> 3;        // 0..31
    const int sk4  = (t & 7) * 4;   // 0,4..28

    f32x4 acc[8];
#pragma unroll
    for (int nf = 0; nf < 8; ++nf) acc[nf] = (f32x4){0.f,0.f,0.f,0.f};

    for (int k0 = 0; k0 < 256; k0 += 32) {
        float4 av = *(const float4*)&x[(size_t)(R0 + srow)*256 + k0 + sk4];
        float4 bv[8];
#pragma unroll
        for (int q = 0; q < 8; ++q)
            bv[q] = *(const float4*)&W[(size_t)(q*32 + srow)*256 + k0 + sk4];
        __syncthreads();   // prev frag reads done before overwrite
        ushort4 a4 = { f2bf(av.x), f2bf(av.y), f2bf(av.z), f2bf(av.w) };
        *(ushort4*)&As[srow*40 + sk4] = a4;
#pragma unroll
        for (int q = 0; q < 8; ++q) {
            ushort4 b4 = { f2bf(bv[q].x), f2bf(bv[q].y), f2bf(bv[q].z), f2bf(bv[q].w) };
            *(ushort4*)&Bs[(q*32 + srow)*40 + sk4] = b4;
        }
        __syncthreads();
        bf16x8 af = *(const bf16x8*)&As[(wr*16 + (l&15))*40 + (l>>4)*8];
#pragma unroll
        for (int nf = 0; nf < 8; ++nf) {
            bf16x8 bfv = *(const bf16x8*)&Bs[(wc*128 + nf*16 + (l&15))*40 + (l>>4)*8];
            acc[nf] = __builtin_amdgcn_mfma_f32_16x16x32_bf16(af, bfv, acc[nf], 0, 0, 0);
        }
    }

    const int b   = R0 / 1600;
    const int n0b = R0 - b*1600;
    const int rowg = wr*16 + (l>>4)*4;   // 0..28, step 4
    float p1[4] = {0,0,0,0}, p2[4] = {0,0,0,0};
#pragma unroll
    for (int nf = 0; nf < 8; ++nf) {
        const int f = wc*128 + nf*16 + (l & 15);
        const float bwv = bW[f], aiv = ai[f], ajv = aj[f];
        float vv[4];
#pragma unroll
        for (int e = 0; e < 4; ++e) {
            float v = acc[nf][e] + bwv;
            vv[e] = v;
            p1[e] = __builtin_fmaf(v, aiv, p1[e]);
            p2[e] = __builtin_fmaf(v, ajv, p2[e]);
        }
        ushort4 o4 = { f2bf(vv[0]), f2bf(vv[1]), f2bf(vv[2]), f2bf(vv[3]) };
        *(ushort4*)&WhT[((size_t)(b*256 + f))*1600 + n0b + rowg] = o4;
    }
#pragma unroll
    for (int m = 1; m < 16; m <<= 1)
#pragma unroll
        for (int e = 0; e < 4; ++e) {
            p1[e] += __shfl_xor(p1[e], m, 64);
            p2[e] += __shfl_xor(p2[e], m, 64);
        }
    if ((l & 15) == 0)
#pragma unroll
        for (int e = 0; e < 4; ++e) {
            part1[wc][rowg + e] = p1[e];
            part2[wc][rowg + e] = p2[e];
        }
    __syncthreads();
    if (t < 32) {
        Wh1[R0 + t] = part1[0][t] + part1[1][t] + bi[0];
        Wh2[R0 + t] = part2[0][t] + part2[1][t] + bj[0];
    }
}

// ---------------- Stage 2: M2[b][i] = max_{j in adj(i)} Wh2[b][j] ----------
// LeakyReLU is monotone -> row max m_i = f(Wh1_i + M2_i): fixes softmax max
// before the flash loop (no online rescaling needed).
__global__ __launch_bounds__(256) void k_m2(
    const int* __restrict__ adj, const float* __restrict__ Wh2,
    float* __restrict__ M2)
{
    const int w = threadIdx.x >> 6, l = threadIdx.x & 63;
    const int i = blockIdx.x * 4 + w;
    float m[8];
#pragma unroll
    for (int b = 0; b < 8; ++b) m[b] = -3.0e38f;
    for (int j0 = 0; j0 < 1600; j0 += 64) {
        int a = adj[(size_t)i*1600 + j0 + l];
#pragma unroll
        for (int b = 0; b < 8; ++b) {
            float v = Wh2[b*1600 + j0 + l];
            m[b] = (a > 0) ? fmaxf(m[b], v) : m[b];
        }
    }
#pragma unroll
    for (int s = 1; s < 64; s <<= 1)
#pragma unroll
        for (int b = 0; b < 8; ++b)
            m[b] = fmaxf(m[b], __shfl_xor(m[b], s, 64));
    if (l == 0)
#pragma unroll
        for (int b = 0; b < 8; ++b)
            M2[b*1600 + i] = m[b];
}

// ---------------- Stage 3: fixed-m flash attention + ELU -------------------
// grid 400 (1D): b = bid&7 (XCD-affine -> WhT[b] stays in one XCD L2),
// i0 = (bid>>3)*32. 512 thr = 8 waves.
// Score phase: wave w owns rows w*4..w*4+3, lane = j. Pure per-lane ALU
// (m fixed, l accumulates per-lane; single reduce at end).
// PV: wave (wr=w>>2, wc=w&3): rows wr*16+16, f-cols wc*64+64.
__global__ __launch_bounds__(512) void k_attn(
    const unsigned short* __restrict__ WhT,
    const float* __restrict__ Wh1, const float* __restrict__ M2,
    const float* __restrict__ Wh2, const int* __restrict__ adj,
    float* __restrict__ out)
{
    __shared__ alignas(16) unsigned short whs[256*64];  // [f][j] swizzled ^((f&7)<<4)
    __shared__ alignas(16) unsigned short pls[32*64];   // [i][j] swizzled ^((i&7)<<4)
    __shared__ float l_s[32];

    const int t = threadIdx.x;
    const int w = t >> 6, l = t & 63;
    const int bid = blockIdx.x;
    const int b = bid & 7;
    const int i0 = (bid >> 3) * 32;
    const int wr = w >> 2, wc = w & 3;

    float wh1r[4], mr[4];
#pragma unroll
    for (int r = 0; r < 4; ++r) {
        int gi = i0 + w*4 + r;
        wh1r[r] = Wh1[b*1600 + gi];
        float s = wh1r[r] + M2[b*1600 + gi];
        mr[r] = s > 0.f ? s : LRELU_ALPHA * s;
    }
    float lsum[4] = {0,0,0,0};
    f32x4 acc[4];
#pragma unroll
    for (int nf = 0; nf < 4; ++nf) acc[nf] = (f32x4){0.f,0.f,0.f,0.f};

    const unsigned short* whtb = WhT + (size_t)b*256*1600;
    const int sfr = w*8 + (l>>3);
    const int sc_ = l & 7;

    for (int jt = 0; jt < 25; ++jt) {
        const int j0 = jt * 64;
        // stage whs: linear LDS dest, inverse-swizzled global source
#pragma unroll
        for (int q = 0; q < 4; ++q) {
            int f = q*64 + sfr;
            int cs = sc_ ^ (f & 7);
            const unsigned short* g = whtb + (size_t)f*1600 + j0 + cs*8;
            unsigned short* lp = &whs[(q*64 + w*8)*64];
            __builtin_amdgcn_global_load_lds(
                (const __attribute__((address_space(1))) unsigned int*)g,
                (__attribute__((address_space(3))) unsigned int*)lp, 16, 0, 0);
        }
        // scores: per-lane only
        float wh2l = Wh2[b*1600 + j0 + l];
#pragma unroll
        for (int r = 0; r < 4; ++r) {
            const int row = w*4 + r;
            int a = adj[(size_t)(i0 + row)*1600 + j0 + l];
            float s = wh1r[r] + wh2l;
            s = s > 0.f ? s : LRELU_ALPHA * s;
            float p = (a > 0) ? __expf(s - mr[r]) : 0.f;
            lsum[r] += p;
            int off = (row*128 + l*2) ^ ((row & 7) << 4);
            *(unsigned short*)((char*)pls + off) = f2bf(p);
        }
        asm volatile("s_waitcnt vmcnt(0)" ::: "memory");
        __syncthreads();
        // PV MFMA
#pragma unroll
        for (int kb = 0; kb < 2; ++kb) {
            const int arow = wr*16 + (l & 15);
            int aoff = (arow*128 + kb*64 + (l>>4)*16) ^ ((arow & 7) << 4);
            bf16x8 af = *(const bf16x8*)((const char*)pls + aoff);
#pragma unroll
            for (int nf = 0; nf < 4; ++nf) {
                int f = wc*64 + nf*16 + (l & 15);
                int boff = (f*128 + kb*64 + (l>>4)*16) ^ ((f & 7) << 4);
                bf16x8 bfv = *(const bf16x8*)((const char*)whs + boff);
                acc[nf] = __builtin_amdgcn_mfma_f32_16x16x32_bf16(af, bfv, acc[nf], 0, 0, 0);
            }
        }
        __syncthreads();
    }
    // final l reduce (once per kernel)
#pragma unroll
    for (int s = 1; s < 64; s <<= 1)
#pragma unroll
        for (int r = 0; r < 4; ++r)
            lsum[r] += __shfl_xor(lsum[r], s, 64);
    if (l == 0)
#pragma unroll
        for (int r = 0; r < 4; ++r) l_s[w*4 + r] = lsum[r];
    __syncthreads();
    float rl[4];
#pragma unroll
    for (int e = 0; e < 4; ++e) rl[e] = 1.f / l_s[wr*16 + (l>>4)*4 + e];
#pragma unroll
    for (int nf = 0; nf < 4; ++nf)
#pragma unroll
        for (int e = 0; e < 4; ++e) {
            int row = wr*16 + (l>>4)*4 + e;
            float v = acc[nf][e] * rl[e];
            v = v > 0.f ? v : expm1f(v);
            out[(size_t)(b*1600 + i0 + row)*256 + wc*64 + nf*16 + (l & 15)] = v;
        }
}

extern "C" void kernel_launch(void* const* d_in, const int* in_sizes, int n_in,
                              void* d_out, int out_size, void* d_ws, size_t ws_size,
                              hipStream_t stream)
{
    const float* h  = (const float*)d_in[0];
    const int* adj  = (const int*)d_in[1];
    const float* W  = (const float*)d_in[2];
    const float* bW = (const float*)d_in[3];
    const float* ai = (const float*)d_in[4];
    const float* bi = (const float*)d_in[5];
    const float* aj = (const float*)d_in[6];
    const float* bj = (const float*)d_in[7];
    float* out = (float*)d_out;

    char* ws = (char*)d_ws;
    unsigned short* WhT = (unsigned short*)ws;          // 6,553,600 B
    float* Wh1 = (float*)(ws + 6553600);                //    51,200 B
    float* Wh2 = Wh1 + 12800;                           //    51,200 B
    float* M2  = Wh2 + 12800;                           //    51,200 B

    k_gemm_fused<<<400, 256, 0, stream>>>(h, W, bW, ai, bi, aj, bj, WhT, Wh1, Wh2);
    k_m2<<<400, 256, 0, stream>>>(adj, Wh2, M2);
    k_attn<<<400, 512, 0, stream>>>(WhT, Wh1, M2, Wh2, adj, out);
}

// Round 5
// 162.208 us; speedup vs baseline: 1.3229x; 1.3229x over previous
//
#include <hip/hip_runtime.h>
#include <hip/hip_bf16.h>

typedef __attribute__((ext_vector_type(8))) short bf16x8;
typedef __attribute__((ext_vector_type(4))) float f32x4;

#define LRELU_ALPHA 0.2f

static __device__ __forceinline__ unsigned short f2bf(float x) {
    unsigned u = __float_as_uint(x);
    u += 0x7fffu + ((u >> 16) & 1u);   // RNE; inputs finite
    return (unsigned short)(u >> 16);
}
// order-preserving float<->uint map for atomicMax on floats
static __device__ __forceinline__ unsigned f2ord(float x) {
    unsigned b = __float_as_uint(x);
    return (b & 0x80000000u) ? ~b : (b | 0x80000000u);
}
static __device__ __forceinline__ float ord2f(unsigned m) {
    unsigned b = (m & 0x80000000u) ? (m ^ 0x80000000u) : ~m;
    return __uint_as_float(b);
}

// ---------------- Stage 0: fp32 -> bf16 (x: 1600 blocks, W: 32 blocks) -----
__global__ __launch_bounds__(256) void k_convert(
    const float* __restrict__ x, const float* __restrict__ W,
    unsigned short* __restrict__ xb, unsigned short* __restrict__ Wb)
{
    const int bid = blockIdx.x;
    const float* src;
    unsigned short* dst;
    size_t base;
    if (bid < 1600) { src = x; dst = xb; base = (size_t)bid * 2048; }
    else            { src = W; dst = Wb; base = (size_t)(bid - 1600) * 2048; }
    const size_t idx = base + (size_t)threadIdx.x * 8;
    float4 v0 = *(const float4*)&src[idx];
    float4 v1 = *(const float4*)&src[idx + 4];
    ushort4 o0 = { f2bf(v0.x), f2bf(v0.y), f2bf(v0.z), f2bf(v0.w) };
    ushort4 o1 = { f2bf(v1.x), f2bf(v1.y), f2bf(v1.z), f2bf(v1.w) };
    *(ushort4*)&dst[idx]     = o0;
    *(ushort4*)&dst[idx + 4] = o1;
}

// ---------------- Stage 1: LDS-free bf16 MFMA GEMM + fused epilogue --------
// Wh = x@W^T + bW (fp32 acc). A/B frags straight from global (Wb is L2-hot).
// Writes WhT[b][f][n] bf16, Wh1/Wh2 fp32 (from fp32 acc), M2g[b] atomic max.
// grid 400 x 256 thr; wave (wr=w>>1: 16-row half, wc=w&1: 128-f half).
__global__ __launch_bounds__(256) void k_gemm_fused(
    const unsigned short* __restrict__ xb, const unsigned short* __restrict__ Wb,
    const float* __restrict__ bW, const float* __restrict__ ai,
    const float* __restrict__ bi, const float* __restrict__ aj,
    const float* __restrict__ bj,
    unsigned short* __restrict__ WhT, float* __restrict__ Wh1,
    float* __restrict__ Wh2, unsigned* __restrict__ M2g)
{
    __shared__ float part1[2][32], part2[2][32];
    const int t = threadIdx.x;
    const int w = t >> 6, l = t & 63;
    const int wr = w >> 1, wc = w & 1;
    const int R0 = blockIdx.x * 32;
    const int arow = R0 + wr*16 + (l & 15);
    const int kg8 = (l >> 4) * 8;

    f32x4 acc[8];
#pragma unroll
    for (int nf = 0; nf < 8; ++nf) acc[nf] = (f32x4){0.f,0.f,0.f,0.f};

#pragma unroll 2
    for (int k0 = 0; k0 < 256; k0 += 32) {
        bf16x8 af = *(const bf16x8*)&xb[(size_t)arow*256 + k0 + kg8];
#pragma unroll
        for (int nf = 0; nf < 8; ++nf) {
            bf16x8 bfv = *(const bf16x8*)&Wb[(size_t)(wc*128 + nf*16 + (l&15))*256 + k0 + kg8];
            acc[nf] = __builtin_amdgcn_mfma_f32_16x16x32_bf16(af, bfv, acc[nf], 0, 0, 0);
        }
    }

    const int b   = R0 / 1600;
    const int n0b = R0 - b*1600;
    const int rowg = wr*16 + (l>>4)*4;
    float p1[4] = {0,0,0,0}, p2[4] = {0,0,0,0};
#pragma unroll
    for (int nf = 0; nf < 8; ++nf) {
        const int f = wc*128 + nf*16 + (l & 15);
        const float bwv = bW[f], aiv = ai[f], ajv = aj[f];
        float vv[4];
#pragma unroll
        for (int e = 0; e < 4; ++e) {
            float v = acc[nf][e] + bwv;
            vv[e] = v;
            p1[e] = __builtin_fmaf(v, aiv, p1[e]);
            p2[e] = __builtin_fmaf(v, ajv, p2[e]);
        }
        ushort4 o4 = { f2bf(vv[0]), f2bf(vv[1]), f2bf(vv[2]), f2bf(vv[3]) };
        *(ushort4*)&WhT[((size_t)(b*256 + f))*1600 + n0b + rowg] = o4;
    }
#pragma unroll
    for (int m = 1; m < 16; m <<= 1)
#pragma unroll
        for (int e = 0; e < 4; ++e) {
            p1[e] += __shfl_xor(p1[e], m, 64);
            p2[e] += __shfl_xor(p2[e], m, 64);
        }
    if ((l & 15) == 0)
#pragma unroll
        for (int e = 0; e < 4; ++e) {
            part1[wc][rowg + e] = p1[e];
            part2[wc][rowg + e] = p2[e];
        }
    __syncthreads();
    if (t < 32) {
        float v1 = part1[0][t] + part1[1][t] + bi[0];
        float v2 = part2[0][t] + part2[1][t] + bj[0];
        Wh1[R0 + t] = v1;
        Wh2[R0 + t] = v2;
        unsigned o = f2ord(v2);
#pragma unroll
        for (int m = 1; m < 32; m <<= 1) {
            unsigned o2 = __shfl_xor(o, m, 64);
            o = (o2 > o) ? o2 : o;
        }
        if (t == 0) atomicMax(&M2g[b], o);
    }
}

// ---------------- Stage 2: pipelined fixed-m flash attention + ELU ---------
// grid 400: b = bid&7 (== XCD -> WhT[b] L2-affine), i0 = (bid>>3)*32.
// 512 thr = 8 waves; wave w: scores rows w*4..+3, PV f-slice [w*32, w*32+32).
// All global operands (B-frags, adj, Wh2) prefetched 1 tile ahead into regs;
// P double-buffered in LDS -> exactly ONE s_barrier per tile, no vmcnt drain.
__global__ __launch_bounds__(512) void k_attn(
    const unsigned short* __restrict__ WhT,
    const float* __restrict__ Wh1, const unsigned* __restrict__ M2g,
    const float* __restrict__ Wh2, const int* __restrict__ adj,
    float* __restrict__ out)
{
    __shared__ alignas(16) unsigned short pls[2][32*64];  // [i][j] ^((i&7)<<4)
    __shared__ float l_s[32];

    const int t = threadIdx.x;
    const int w = t >> 6, l = t & 63;
    const int b = blockIdx.x & 7;
    const int i0 = (blockIdx.x >> 3) * 32;

    const float m2v = ord2f(M2g[b]);
    float wh1r[4], mr[4];
#pragma unroll
    for (int r = 0; r < 4; ++r) {
        int gi = i0 + w*4 + r;
        wh1r[r] = Wh1[b*1600 + gi];
        float s = wh1r[r] + m2v;            // >= true masked row max (monotone)
        mr[r] = s > 0.f ? s : LRELU_ALPHA * s;
    }
    float lsum[4] = {0.f,0.f,0.f,0.f};
    f32x4 acc[2][2];
#pragma unroll
    for (int mi = 0; mi < 2; ++mi)
#pragma unroll
        for (int nf = 0; nf < 2; ++nf) acc[mi][nf] = (f32x4){0.f,0.f,0.f,0.f};

    const unsigned short* whtb = WhT + (size_t)b*256*1600;
    const unsigned short* bp0 = whtb + (size_t)(w*32 +  0 + (l&15))*1600 + (l>>4)*8;
    const unsigned short* bp1 = whtb + (size_t)(w*32 + 16 + (l&15))*1600 + (l>>4)*8;

    // prologue: prefetch tile 0
    int ac[4]; float wcur; bf16x8 bc[2][2];
#pragma unroll
    for (int r = 0; r < 4; ++r) ac[r] = adj[(size_t)(i0 + w*4 + r)*1600 + l];
    wcur = Wh2[b*1600 + l];
    bc[0][0] = *(const bf16x8*)(bp0);      bc[0][1] = *(const bf16x8*)(bp0 + 32);
    bc[1][0] = *(const bf16x8*)(bp1);      bc[1][1] = *(const bf16x8*)(bp1 + 32);

    for (int jt = 0; jt < 25; ++jt) {
        const int cb = jt & 1;
        int an[4]; float wn; bf16x8 bn[2][2];
        if (jt < 24) {
            const int j1 = (jt + 1) * 64;
            bn[0][0] = *(const bf16x8*)(bp0 + j1);      bn[0][1] = *(const bf16x8*)(bp0 + j1 + 32);
            bn[1][0] = *(const bf16x8*)(bp1 + j1);      bn[1][1] = *(const bf16x8*)(bp1 + j1 + 32);
#pragma unroll
            for (int r = 0; r < 4; ++r)
                an[r] = adj[(size_t)(i0 + w*4 + r)*1600 + j1 + l];
            wn = Wh2[b*1600 + j1 + l];
        }
        __builtin_amdgcn_sched_barrier(0);   // pin prefetch issue here
        // scores (pure per-lane VALU; operands prefetched last tile)
#pragma unroll
        for (int r = 0; r < 4; ++r) {
            const int row = w*4 + r;
            float s = wh1r[r] + wcur;
            s = s > 0.f ? s : LRELU_ALPHA * s;
            float p = (ac[r] > 0) ? __expf(s - mr[r]) : 0.f;
            lsum[r] += p;
            int off = (row*128 + l*2) ^ ((row & 7) << 4);
            *(unsigned short*)((char*)pls[cb] + off) = f2bf(p);
        }
        asm volatile("s_waitcnt lgkmcnt(0)" ::: "memory");
        __builtin_amdgcn_sched_barrier(0);
        __builtin_amdgcn_s_barrier();        // pls[cb] ready; prev reads done
        // PV: A from pls[cb], B from regs (global-prefetched)
#pragma unroll
        for (int kb = 0; kb < 2; ++kb) {
            bf16x8 af[2];
#pragma unroll
            for (int mi = 0; mi < 2; ++mi) {
                int ar = mi*16 + (l & 15);
                int aoff = (ar*128 + kb*64 + (l>>4)*16) ^ ((ar & 7) << 4);
                af[mi] = *(const bf16x8*)((const char*)pls[cb] + aoff);
            }
#pragma unroll
            for (int mi = 0; mi < 2; ++mi)
#pragma unroll
                for (int nf = 0; nf < 2; ++nf)
                    acc[mi][nf] = __builtin_amdgcn_mfma_f32_16x16x32_bf16(
                        af[mi], bc[nf][kb], acc[mi][nf], 0, 0, 0);
        }
        if (jt < 24) {
#pragma unroll
            for (int r = 0; r < 4; ++r) ac[r] = an[r];
            wcur = wn;
#pragma unroll
            for (int nf = 0; nf < 2; ++nf)
#pragma unroll
                for (int kb = 0; kb < 2; ++kb) bc[nf][kb] = bn[nf][kb];
        }
    }
    // final l reduce (once)
#pragma unroll
    for (int s2 = 1; s2 < 64; s2 <<= 1)
#pragma unroll
        for (int r = 0; r < 4; ++r)
            lsum[r] += __shfl_xor(lsum[r], s2, 64);
    if (l == 0)
#pragma unroll
        for (int r = 0; r < 4; ++r) l_s[w*4 + r] = lsum[r];
    __syncthreads();
#pragma unroll
    for (int mi = 0; mi < 2; ++mi)
#pragma unroll
        for (int e = 0; e < 4; ++e) {
            const int row = mi*16 + (l>>4)*4 + e;
            const float rl = 1.f / l_s[row];
#pragma unroll
            for (int nf = 0; nf < 2; ++nf) {
                float v = acc[mi][nf][e] * rl;
                v = v > 0.f ? v : expm1f(v);
                out[(size_t)(b*1600 + i0 + row)*256 + w*32 + nf*16 + (l & 15)] = v;
            }
        }
}

extern "C" void kernel_launch(void* const* d_in, const int* in_sizes, int n_in,
                              void* d_out, int out_size, void* d_ws, size_t ws_size,
                              hipStream_t stream)
{
    const float* h  = (const float*)d_in[0];
    const int* adj  = (const int*)d_in[1];
    const float* W  = (const float*)d_in[2];
    const float* bW = (const float*)d_in[3];
    const float* ai = (const float*)d_in[4];
    const float* bi = (const float*)d_in[5];
    const float* aj = (const float*)d_in[6];
    const float* bj = (const float*)d_in[7];
    float* out = (float*)d_out;

    char* ws = (char*)d_ws;
    unsigned short* xb  = (unsigned short*)ws;                    // 6,553,600 B
    unsigned short* Wb  = (unsigned short*)(ws + 6553600);        //   131,072 B
    unsigned short* WhT = (unsigned short*)(ws + 6684672);        // 6,553,600 B
    float* Wh1 = (float*)(ws + 13238272);                         //    51,200 B
    float* Wh2 = (float*)(ws + 13289472);                         //    51,200 B
    unsigned* M2g = (unsigned*)(ws + 13340672);                   //        32 B

    hipMemsetAsync(M2g, 0, 32, stream);   // ordered-uint -inf sentinel
    k_convert<<<1632, 256, 0, stream>>>(h, W, xb, Wb);
    k_gemm_fused<<<400, 256, 0, stream>>>(xb, Wb, bW, ai, bi, aj, bj,
                                          WhT, Wh1, Wh2, M2g);
    k_attn<<<400, 512, 0, stream>>>(WhT, Wh1, M2g, Wh2, adj, out);
}